// Round 3
// baseline (18889.888 us; speedup 1.0000x reference)
//
#include <hip/hip_runtime.h>
#include <math.h>

#define S_LEN 256
#define BATCH 64
#define EDIM  256
#define HDIM  512
#define CHUNK 64
#define NCHUNK 4
#define SCAN_WGS 128

typedef float f32x4 __attribute__((ext_vector_type(4)));

// ---- cache-bypassing (coherence-point) 16B load/store: sc0 sc1 ----
__device__ __forceinline__ void ld_b128_sc(f32x4* v, const float* p) {
  asm volatile("global_load_dwordx4 %0, %1, off sc0 sc1"
               : "=v"(*v) : "v"(p) : "memory");
}
__device__ __forceinline__ void st_b128_sc(float* p, f32x4 v) {
  asm volatile("global_store_dwordx4 %0, %1, off sc0 sc1"
               :: "v"(p), "v"(v) : "memory");
}

// ---------------- Phase A: gi = emb[sent] @ Wih^T + bih  ----------------
// grid (32, 12, 2): 128x128 tiles over M=4096 (64 s x 64 b), N=1536. K=256.
__global__ __launch_bounds__(256, 3) void gi_gemm(
    const int* __restrict__ sent, const float* __restrict__ emb,
    const float* __restrict__ Wih_f, const float* __restrict__ bih_f,
    const float* __restrict__ Wih_b, const float* __restrict__ bih_b,
    float* __restrict__ gi, int chunk)
{
  const int d  = blockIdx.z;
  const int bx = blockIdx.x;
  const int by = blockIdx.y;
  const float* W    = d ? Wih_b : Wih_f;
  const float* bias = d ? bih_b : bih_f;
  const int sbase = (d == 0) ? chunk * CHUNK : (S_LEN - CHUNK - chunk * CHUNK);

  __shared__ int    tok[128];
  __shared__ float4 As4[128][8];
  __shared__ float4 Bs4[128][8];

  const int tid = threadIdx.x;
  if (tid < 128) {
    int s_lc = 2 * bx + (tid >> 6);
    int b    = tid & 63;
    tok[tid] = sent[(sbase + s_lc) * BATCH + b];
  }

  float acc[8][8];
#pragma unroll
  for (int i = 0; i < 8; ++i)
#pragma unroll
    for (int j = 0; j < 8; ++j) acc[i][j] = 0.f;

  const int tb = tid & 15;
  const int tn = tid >> 4;

  for (int kc = 0; kc < 8; ++kc) {
    __syncthreads();
#pragma unroll
    for (int it = 0; it < 4; ++it) {
      int flat = tid + 256 * it;          // 0..1023
      int row  = flat >> 3;
      int k4   = flat & 7;
      int sw   = k4 ^ (row & 7) ^ ((row >> 3) & 7);
      As4[row][sw] = *(const float4*)&emb[(size_t)tok[row] * EDIM + kc * 32 + 4 * k4];
      Bs4[row][sw] = *(const float4*)&W[(size_t)(by * 128 + row) * EDIM + kc * 32 + 4 * k4];
    }
    __syncthreads();
#pragma unroll
    for (int k4 = 0; k4 < 8; ++k4) {
      float4 a[8];
#pragma unroll
      for (int i = 0; i < 8; ++i)
        a[i] = As4[8 * tb + i][k4 ^ i ^ (tb & 7)];
#pragma unroll
      for (int j = 0; j < 8; ++j) {
        float4 bf = Bs4[8 * tn + j][k4 ^ j ^ (tn & 7)];
#pragma unroll
        for (int i = 0; i < 8; ++i)
          acc[i][j] += a[i].x * bf.x + a[i].y * bf.y
                     + a[i].z * bf.z + a[i].w * bf.w;
      }
    }
  }

  const int s_lc = 2 * bx + (tb >> 3);
  const int brow = 8 * (tb & 7);
#pragma unroll
  for (int j = 0; j < 8; ++j) {
    int n = by * 128 + 8 * tn + j;
    float bs = bias[n];
    int g = n >> 9, u = n & 511;
    size_t base = ((((size_t)d * CHUNK + s_lc) * 3 + g) * HDIM + u) * BATCH + brow;
    float4 v0 = { acc[0][j] + bs, acc[1][j] + bs, acc[2][j] + bs, acc[3][j] + bs };
    float4 v1 = { acc[4][j] + bs, acc[5][j] + bs, acc[6][j] + bs, acc[7][j] + bs };
    *(float4*)&gi[base]     = v0;
    *(float4*)&gi[base + 4] = v1;
  }
}

// ---------------- Phase B: barriered recurrent scan ----------------
// 128 WGs x 256 thr. WG = (dir, 8 hidden units), all 64 batch rows.
// gi layout: [d][lt][g][u][b]; hs layout: [d][t][b][k].
// h exchanged via sc0sc1 (coherence-point) ops => NO cache invalidates,
// Whh/gi stay L2-resident across all 64 steps.
__global__ __launch_bounds__(256, 1) void scan_kernel(
    const float* __restrict__ gi, float* __restrict__ hs,
    const float* __restrict__ Whh_f, const float* __restrict__ bhh_f,
    const float* __restrict__ Whh_b, const float* __restrict__ bhh_b,
    unsigned* cnt, int chunk)
{
  const int w   = blockIdx.x;
  const int d   = w >> 6;
  const int uc  = w & 63;
  const int tid = threadIdx.x;
  const int tx  = tid & 63;
  const int ty  = __builtin_amdgcn_readfirstlane(tid >> 6);   // 0..3, wave-uniform

  const float* Whh = d ? Whh_b : Whh_f;
  const float* bhh = d ? bhh_b : bhh_f;
  const int u0 = 8 * uc + 2 * ty;

  // one full h(t-1) tile [64 b][512 k], kc-slice layout: col = 132*kc + klocal
  // row stride 532 floats: 532 mod 32 = 20 (4 mod 8 = 4, odd float4 phase)
  __shared__ float hl[64][532];
  __shared__ float hb[64][12];

  const float br0 = bhh[u0],          br1 = bhh[u0 + 1];
  const float bz0 = bhh[512 + u0],    bz1 = bhh[512 + u0 + 1];
  const float bn0 = bhh[1024 + u0],   bn1 = bhh[1024 + u0 + 1];

  const int kcu = u0 >> 7;            // kc slice holding this thread's own units

  for (int l = 0; l < CHUNK; ++l) {
    const int gs      = CHUNK * chunk + l;
    const int lt      = (d == 0) ? l : (CHUNK - 1 - l);
    const int t_store = (d == 0) ? gs : (S_LEN - 1 - gs);
    const int t_prev  = (d == 0) ? (gs - 1) : (S_LEN - gs);

    const float* gb = gi + ((size_t)d * CHUNK + lt) * 3 * HDIM * BATCH;
    float ir0 = gb[((size_t)0 * HDIM + u0    ) * BATCH + tx];
    float ir1 = gb[((size_t)0 * HDIM + u0 + 1) * BATCH + tx];
    float iz0 = gb[((size_t)1 * HDIM + u0    ) * BATCH + tx];
    float iz1 = gb[((size_t)1 * HDIM + u0 + 1) * BATCH + tx];
    float in0 = gb[((size_t)2 * HDIM + u0    ) * BATCH + tx];
    float in1 = gb[((size_t)2 * HDIM + u0 + 1) * BATCH + tx];

    float aR0 = 0, aR1 = 0, aZ0 = 0, aZ1 = 0, aN0 = 0, aN1 = 0;
    float hp0 = 0, hp1 = 0;

    if (gs > 0) {
      const float* hp = hs + ((size_t)d * S_LEN + t_prev) * HDIM * BATCH;
      // ---- counted-vmcnt pipelined staging: 4 groups x 8 float4/thread ----
      f32x4 bufA[8], bufB[8];
#define LDG(BUF, G)                                                          \
  _Pragma("unroll")                                                          \
  for (int j = 0; j < 8; ++j) {                                              \
    int flat = tid + 256 * (8 * (G) + j);                                    \
    ld_b128_sc(&BUF[j], &hp[(size_t)(flat >> 7) * HDIM + 4 * (flat & 127)]); \
  }
#define STG(BUF, G)                                                          \
  _Pragma("unroll")                                                          \
  for (int j = 0; j < 8; ++j) {                                              \
    int flat = tid + 256 * (8 * (G) + j);                                    \
    int b = flat >> 7, kq = flat & 127;                                      \
    *(f32x4*)&hl[b][132 * (kq >> 5) + 4 * (kq & 31)] = BUF[j];               \
  }
      LDG(bufA, 0)
      LDG(bufB, 1)
      asm volatile("s_waitcnt vmcnt(8)" ::: "memory");
      __builtin_amdgcn_sched_barrier(0);
      STG(bufA, 0)
      LDG(bufA, 2)
      asm volatile("s_waitcnt vmcnt(8)" ::: "memory");
      __builtin_amdgcn_sched_barrier(0);
      STG(bufB, 1)
      LDG(bufB, 3)
      asm volatile("s_waitcnt vmcnt(8)" ::: "memory");
      __builtin_amdgcn_sched_barrier(0);
      STG(bufA, 2)
      asm volatile("s_waitcnt vmcnt(0)" ::: "memory");
      __builtin_amdgcn_sched_barrier(0);
      STG(bufB, 3)
#undef LDG
#undef STG
      __syncthreads();

      hp0 = hl[tx][132 * kcu + ((u0    ) & 127)];
      hp1 = hl[tx][132 * kcu + ((u0 + 1) & 127)];

      for (int kc = 0; kc < 4; ++kc) {
        const float* hrow = &hl[tx][132 * kc];
        const float* wr0p = Whh + (size_t)(u0           ) * HDIM + kc * 128;
        const float* wr1p = Whh + (size_t)(u0 + 1       ) * HDIM + kc * 128;
        const float* wz0p = Whh + (size_t)(512 + u0     ) * HDIM + kc * 128;
        const float* wz1p = Whh + (size_t)(512 + u0 + 1 ) * HDIM + kc * 128;
        const float* wn0p = Whh + (size_t)(1024 + u0    ) * HDIM + kc * 128;
        const float* wn1p = Whh + (size_t)(1024 + u0 + 1) * HDIM + kc * 128;
#pragma unroll 4
        for (int kk = 0; kk < 128; kk += 4) {
          float4 h4  = *(const float4*)&hrow[kk];
          float4 wr0 = *(const float4*)&wr0p[kk];
          float4 wr1 = *(const float4*)&wr1p[kk];
          float4 wz0 = *(const float4*)&wz0p[kk];
          float4 wz1 = *(const float4*)&wz1p[kk];
          float4 wn0 = *(const float4*)&wn0p[kk];
          float4 wn1 = *(const float4*)&wn1p[kk];
          aR0 += h4.x * wr0.x + h4.y * wr0.y + h4.z * wr0.z + h4.w * wr0.w;
          aR1 += h4.x * wr1.x + h4.y * wr1.y + h4.z * wr1.z + h4.w * wr1.w;
          aZ0 += h4.x * wz0.x + h4.y * wz0.y + h4.z * wz0.z + h4.w * wz0.w;
          aZ1 += h4.x * wz1.x + h4.y * wz1.y + h4.z * wz1.z + h4.w * wz1.w;
          aN0 += h4.x * wn0.x + h4.y * wn0.y + h4.z * wn0.z + h4.w * wn0.w;
          aN1 += h4.x * wn1.x + h4.y * wn1.y + h4.z * wn1.z + h4.w * wn1.w;
        }
      }
    }

    float r0 = 1.f / (1.f + expf(-(ir0 + aR0 + br0)));
    float r1 = 1.f / (1.f + expf(-(ir1 + aR1 + br1)));
    float z0 = 1.f / (1.f + expf(-(iz0 + aZ0 + bz0)));
    float z1 = 1.f / (1.f + expf(-(iz1 + aZ1 + bz1)));
    float n0 = tanhf(in0 + r0 * (aN0 + bn0));
    float n1 = tanhf(in1 + r1 * (aN1 + bn1));
    float h0n = (1.f - z0) * n0 + z0 * hp0;
    float h1n = (1.f - z1) * n1 + z1 * hp1;

    __syncthreads();
    hb[tx][2 * ty    ] = h0n;
    hb[tx][2 * ty + 1] = h1n;
    __syncthreads();
    if (tid < 128) {
      int row = tid >> 1, q = tid & 1;
      f32x4 v = *(const f32x4*)&hb[row][4 * q];
      st_b128_sc(&hs[(((size_t)d * S_LEN + t_store) * BATCH + row) * HDIM + 8 * uc + 4 * q], v);
    }

    // ---- device-wide barrier: relaxed agent atomics, 8 padded counters ----
    __syncthreads();   // drains each wave's stores (vmcnt 0) before arrive
    if (tid == 0)
      __hip_atomic_fetch_add(&cnt[(w & 7) << 4], 1u,
                             __ATOMIC_RELAXED, __HIP_MEMORY_SCOPE_AGENT);
    if (tid < 8) {
      unsigned tgt = 16u * (unsigned)(gs + 1);
      while (__hip_atomic_load(&cnt[tid << 4],
                               __ATOMIC_RELAXED, __HIP_MEMORY_SCOPE_AGENT) < tgt)
        __builtin_amdgcn_s_sleep(1);
    }
    __syncthreads();
  }
}

// ---------------- Phase C: pz / z ----------------
__global__ __launch_bounds__(256) void pz_kernel(
    const float* __restrict__ hs, const float* __restrict__ zW,
    const float* __restrict__ zb_, const float* __restrict__ noise,
    float* __restrict__ out)
{
  const int gtid = blockIdx.x * 256 + threadIdx.x;
  const int wave = gtid >> 6;
  const int lane = threadIdx.x & 63;
  const float zb = zb_[0];
  float4 w1 = *(const float4*)&zW[lane * 8];
  float4 w2 = *(const float4*)&zW[lane * 8 + 4];
  float4 w3 = *(const float4*)&zW[512 + lane * 8];
  float4 w4 = *(const float4*)&zW[512 + lane * 8 + 4];
  for (int r = wave; r < S_LEN * BATCH; r += 1024) {
    const float* hf  = hs + (size_t)r * HDIM;
    const float* hbk = hs + (size_t)(S_LEN * BATCH + r) * HDIM;
    float4 a1 = *(const float4*)&hf[lane * 8];
    float4 a2 = *(const float4*)&hf[lane * 8 + 4];
    float4 b1 = *(const float4*)&hbk[lane * 8];
    float4 b2 = *(const float4*)&hbk[lane * 8 + 4];
    float acc = a1.x * w1.x + a1.y * w1.y + a1.z * w1.z + a1.w * w1.w
              + a2.x * w2.x + a2.y * w2.y + a2.z * w2.z + a2.w * w2.w
              + b1.x * w3.x + b1.y * w3.y + b1.z * w3.z + b1.w * w3.w
              + b2.x * w4.x + b2.y * w4.y + b2.z * w4.z + b2.w * w4.w;
#pragma unroll
    for (int off = 32; off > 0; off >>= 1) acc += __shfl_down(acc, off, 64);
    if (lane == 0) {
      float p = 1.f / (1.f + expf(-(acc + zb)));
      out[r] = p;
      out[S_LEN * BATCH + r] = (noise[r] < p) ? 1.f : 0.f;
    }
  }
}

// ---------------- Phase D: per-column stable compaction ----------------
__global__ __launch_bounds__(256) void rat_kernel(
    const int* __restrict__ sent, float* __restrict__ out)
{
  const int b = blockIdx.x;
  const int s = threadIdx.x;
  __shared__ int ps[256];
  const int z = (out[S_LEN * BATCH + s * BATCH + b] > 0.5f) ? 1 : 0;
  ps[s] = z;
  __syncthreads();
#pragma unroll
  for (int off = 1; off < 256; off <<= 1) {
    int v = (s >= off) ? ps[s - off] : 0;
    __syncthreads();
    ps[s] += v;
    __syncthreads();
  }
  const int incl  = ps[s];
  const int total = ps[255];
  const int pos   = incl - z;
  if (z) out[2 * S_LEN * BATCH + pos * BATCH + b] = (float)sent[s * BATCH + b];
  if (s >= total) out[2 * S_LEN * BATCH + s * BATCH + b] = 0.f;
  if (s == 0) out[3 * S_LEN * BATCH + b] = (float)total;
}

extern "C" void kernel_launch(void* const* d_in, const int* in_sizes, int n_in,
                              void* d_out, int out_size, void* d_ws, size_t ws_size,
                              hipStream_t stream)
{
  const int*   sent  = (const int*)  d_in[0];
  const float* noise = (const float*)d_in[1];
  const float* emb   = (const float*)d_in[2];
  const float* Wih_f = (const float*)d_in[3];
  const float* Whh_f = (const float*)d_in[4];
  const float* bih_f = (const float*)d_in[5];
  const float* bhh_f = (const float*)d_in[6];
  const float* Wih_b = (const float*)d_in[7];
  const float* Whh_b = (const float*)d_in[8];
  const float* bih_b = (const float*)d_in[9];
  const float* bhh_b = (const float*)d_in[10];
  const float* zW    = (const float*)d_in[11];
  const float* zb    = (const float*)d_in[12];
  float* out = (float*)d_out;

  float* gi = (float*)d_ws;                                    // 2*64*1536*64 f32 = 50.3 MB
  float* hs = gi + (size_t)2 * CHUNK * 3 * HDIM * BATCH;       // 2*256*64*512 f32 = 67.1 MB
  unsigned* cnt = (unsigned*)(hs + (size_t)2 * S_LEN * HDIM * BATCH);

  (void)hipMemsetAsync(cnt, 0, 1024, stream);
  for (int c = 0; c < NCHUNK; ++c) {
    gi_gemm<<<dim3(32, 12, 2), 256, 0, stream>>>(sent, emb, Wih_f, bih_f, Wih_b, bih_b, gi, c);
    scan_kernel<<<dim3(SCAN_WGS), 256, 0, stream>>>(gi, hs, Whh_f, bhh_f, Whh_b, bhh_b, cnt, c);
  }
  pz_kernel<<<dim3(256), 256, 0, stream>>>(hs, zW, zb, noise, out);
  rat_kernel<<<dim3(BATCH), 256, 0, stream>>>(sent, out);
}

// Round 4
// 5434.967 us; speedup vs baseline: 3.4756x; 3.4756x over previous
//
#include <hip/hip_runtime.h>
#include <math.h>

#define S_LEN 256
#define BATCH 64
#define EDIM  256
#define HDIM  512

typedef float f32x4 __attribute__((ext_vector_type(4)));

// ---- cache-bypassing (coherence-point) 16B load/store: sc0 sc1 ----
__device__ __forceinline__ void ld_b128_sc(f32x4* v, const float* p) {
  asm volatile("global_load_dwordx4 %0, %1, off sc0 sc1"
               : "=v"(*v) : "v"(p) : "memory");
}
__device__ __forceinline__ void st_b128_sc(float* p, f32x4 v) {
  asm volatile("global_store_dwordx4 %0, %1, off sc0 sc1"
               :: "v"(p), "v"(v) : "memory");
}

// ---------------- Phase A: gi = emb[sent] @ Wih^T + bih ----------------
// 512 thr/block, 128x128 tile, 8Mx4N micro (no spills).
// grid (nslots/2, 12, 2). gi layout: [d][slot][g][u][b].
__global__ __launch_bounds__(512) void gi_gemm(
    const int* __restrict__ sent, const float* __restrict__ emb,
    const float* __restrict__ Wih_f, const float* __restrict__ bih_f,
    const float* __restrict__ Wih_b, const float* __restrict__ bih_b,
    float* __restrict__ gi, int slot_base, int nslots)
{
  const int d  = blockIdx.z;
  const int bx = blockIdx.x;
  const int by = blockIdx.y;
  const float* W    = d ? Wih_b : Wih_f;
  const float* bias = d ? bih_b : bih_f;

  __shared__ int    tok[128];
  __shared__ float4 As4[128][8];
  __shared__ float4 Bs4[128][8];

  const int tid = threadIdx.x;
  if (tid < 128) {
    int s_lc = 2 * bx + (tid >> 6);
    int slot = slot_base + s_lc;
    int srow = (d == 0) ? slot : (S_LEN - 1 - slot);
    tok[tid] = sent[srow * BATCH + (tid & 63)];
  }

  float acc[8][4];
#pragma unroll
  for (int i = 0; i < 8; ++i)
#pragma unroll
    for (int j = 0; j < 4; ++j) acc[i][j] = 0.f;

  const int tb = tid & 15;   // M group: slot pair row block
  const int tn = tid >> 4;   // 0..31: N group of 4

  for (int kc = 0; kc < 8; ++kc) {
    __syncthreads();
#pragma unroll
    for (int it = 0; it < 2; ++it) {
      int flat = tid + 512 * it;          // 0..1023
      int row  = flat >> 3;
      int k4   = flat & 7;
      int sw   = k4 ^ (row & 7) ^ ((row >> 3) & 7);
      As4[row][sw] = *(const float4*)&emb[(size_t)tok[row] * EDIM + kc * 32 + 4 * k4];
      Bs4[row][sw] = *(const float4*)&W[(size_t)(by * 128 + row) * EDIM + kc * 32 + 4 * k4];
    }
    __syncthreads();
#pragma unroll
    for (int k4 = 0; k4 < 8; ++k4) {
      float4 a[8];
#pragma unroll
      for (int i = 0; i < 8; ++i)
        a[i] = As4[8 * tb + i][k4 ^ i ^ (tb & 7)];
#pragma unroll
      for (int j = 0; j < 4; ++j) {
        int r = 4 * tn + j;
        float4 bf = Bs4[r][k4 ^ (r & 7) ^ ((r >> 3) & 7)];
#pragma unroll
        for (int i = 0; i < 8; ++i)
          acc[i][j] += a[i].x * bf.x + a[i].y * bf.y
                     + a[i].z * bf.z + a[i].w * bf.w;
      }
    }
  }

  const int s_lc = 2 * bx + (tb >> 3);
  const int brow = 8 * (tb & 7);
#pragma unroll
  for (int j = 0; j < 4; ++j) {
    int n = by * 128 + 4 * tn + j;
    float bs = bias[n];
    int g = n >> 9, u = n & 511;
    size_t base = ((((size_t)d * nslots + s_lc) * 3 + g) * HDIM + u) * BATCH + brow;
    float4 v0 = { acc[0][j] + bs, acc[1][j] + bs, acc[2][j] + bs, acc[3][j] + bs };
    float4 v1 = { acc[4][j] + bs, acc[5][j] + bs, acc[6][j] + bs, acc[7][j] + bs };
    *(float4*)&gi[base]     = v0;
    *(float4*)&gi[base + 4] = v1;
  }
}

// ---------------- Phase B: barriered recurrent scan (v2) ----------------
// 256 WGs x 256 thr. WG = (dir, 4 hidden units); 1 unit per wave.
// Whh rows (12 x 512) cached in LDS once. h exchanged via sc0sc1.
__global__ __launch_bounds__(256, 1) void scan_kernel(
    const float* __restrict__ gi, float* __restrict__ hs,
    const float* __restrict__ Whh_f, const float* __restrict__ bhh_f,
    const float* __restrict__ Whh_b, const float* __restrict__ bhh_b,
    unsigned* cnt, int step0, int nsteps)
{
  const int w   = blockIdx.x;
  const int d   = w >> 7;
  const int ub  = w & 127;
  const int tid = threadIdx.x;
  const int tx  = tid & 63;
  const int ty  = __builtin_amdgcn_readfirstlane(tid >> 6);   // 0..3 wave-uniform
  const int u   = 4 * ub + ty;                                 // this wave's unit

  const float* Whh = d ? Whh_b : Whh_f;
  const float* bhh = d ? bhh_b : bhh_f;

  __shared__ float whl[12][512];   // rows: tyw*3+g  (broadcast reads)
  __shared__ float hl[64][516];    // h(t-1): [batch][k]; 516 = 4*129, conflict-optimal
  __shared__ float hb[64][4];

  // stage Whh rows for this WG's 4 units (once per dispatch)
#pragma unroll
  for (int it = 0; it < 6; ++it) {
    int flat = tid + 256 * it;          // 0..1535 float4s
    int wrow = flat >> 7;               // 0..11
    int c4   = flat & 127;
    int tyw  = wrow / 3, g = wrow % 3;
    *(f32x4*)&whl[wrow][4 * c4] =
        *(const f32x4*)&Whh[(size_t)(g * HDIM + 4 * ub + tyw) * HDIM + 4 * c4];
  }
  __syncthreads();

  const float br = bhh[u];
  const float bz = bhh[512 + u];
  const float bn = bhh[1024 + u];
  const float* wR = &whl[ty * 3 + 0][0];
  const float* wZ = &whl[ty * 3 + 1][0];
  const float* wN = &whl[ty * 3 + 2][0];

  for (int l = 0; l < nsteps; ++l) {
    const int gs      = step0 + l;
    const int t_store = (d == 0) ? gs : (S_LEN - 1 - gs);
    const int t_prev  = (d == 0) ? (gs - 1) : (S_LEN - gs);

    const float* gb = gi + ((size_t)d * nsteps + l) * 3 * HDIM * BATCH;
    float ir  = gb[((size_t)0 * HDIM + u) * BATCH + tx];
    float iz  = gb[((size_t)1 * HDIM + u) * BATCH + tx];
    float in_ = gb[((size_t)2 * HDIM + u) * BATCH + tx];

    float aR = 0.f, aZ = 0.f, aN = 0.f, hp = 0.f;

    if (gs > 0) {
      const float* hpg = hs + ((size_t)d * S_LEN + t_prev) * HDIM * BATCH;
      f32x4 bufA[8], bufB[8];
#define LDG(BUF, G)                                                           \
  _Pragma("unroll")                                                           \
  for (int j = 0; j < 8; ++j) {                                               \
    int flat = tid + 256 * (8 * (G) + j);                                     \
    ld_b128_sc(&BUF[j], &hpg[(size_t)(flat >> 7) * HDIM + 4 * (flat & 127)]); \
  }
#define STG(BUF, G)                                                           \
  _Pragma("unroll")                                                           \
  for (int j = 0; j < 8; ++j) {                                               \
    int flat = tid + 256 * (8 * (G) + j);                                     \
    *(f32x4*)&hl[flat >> 7][4 * (flat & 127)] = BUF[j];                       \
  }
      LDG(bufA, 0)
      LDG(bufB, 1)
      asm volatile("s_waitcnt vmcnt(8)" ::: "memory");
      __builtin_amdgcn_sched_barrier(0);
      STG(bufA, 0)
      LDG(bufA, 2)
      asm volatile("s_waitcnt vmcnt(8)" ::: "memory");
      __builtin_amdgcn_sched_barrier(0);
      STG(bufB, 1)
      LDG(bufB, 3)
      asm volatile("s_waitcnt vmcnt(8)" ::: "memory");
      __builtin_amdgcn_sched_barrier(0);
      STG(bufA, 2)
      asm volatile("s_waitcnt vmcnt(0)" ::: "memory");
      __builtin_amdgcn_sched_barrier(0);
      STG(bufB, 3)
#undef LDG
#undef STG
      __syncthreads();

      hp = hl[tx][u];
      const float* hrow = &hl[tx][0];
#pragma unroll 4
      for (int kk = 0; kk < 512; kk += 4) {
        f32x4 h4  = *(const f32x4*)&hrow[kk];
        f32x4 w4r = *(const f32x4*)&wR[kk];
        f32x4 w4z = *(const f32x4*)&wZ[kk];
        f32x4 w4n = *(const f32x4*)&wN[kk];
        aR += h4.x * w4r.x + h4.y * w4r.y + h4.z * w4r.z + h4.w * w4r.w;
        aZ += h4.x * w4z.x + h4.y * w4z.y + h4.z * w4z.z + h4.w * w4z.w;
        aN += h4.x * w4n.x + h4.y * w4n.y + h4.z * w4n.z + h4.w * w4n.w;
      }
    }

    float r  = 1.f / (1.f + expf(-(ir + aR + br)));
    float zg = 1.f / (1.f + expf(-(iz + aZ + bz)));
    float n  = tanhf(in_ + r * (aN + bn));
    float hn = (1.f - zg) * n + zg * hp;

    __syncthreads();
    hb[tx][ty] = hn;
    __syncthreads();
    if (tid < 64) {
      f32x4 v = *(const f32x4*)&hb[tid][0];
      st_b128_sc(&hs[(((size_t)d * S_LEN + t_store) * BATCH + tid) * HDIM + 4 * ub], v);
      asm volatile("s_waitcnt vmcnt(0)" ::: "memory");
    }

    // ---- device-wide barrier: relaxed agent atomics, 8 padded counters ----
    __syncthreads();
    if (tid == 0)
      __hip_atomic_fetch_add(&cnt[(w & 7) << 4], 1u,
                             __ATOMIC_RELAXED, __HIP_MEMORY_SCOPE_AGENT);
    if (tid < 8) {
      unsigned tgt = 32u * (unsigned)(gs + 1);
      while (__hip_atomic_load(&cnt[tid << 4],
                               __ATOMIC_RELAXED, __HIP_MEMORY_SCOPE_AGENT) < tgt)
        __builtin_amdgcn_s_sleep(1);
    }
    __syncthreads();
  }
}

// ---------------- Phase C: pz / z ----------------
__global__ __launch_bounds__(256) void pz_kernel(
    const float* __restrict__ hs, const float* __restrict__ zW,
    const float* __restrict__ zb_, const float* __restrict__ noise,
    float* __restrict__ out)
{
  const int gtid = blockIdx.x * 256 + threadIdx.x;
  const int wave = gtid >> 6;
  const int lane = threadIdx.x & 63;
  const float zb = zb_[0];
  float4 w1 = *(const float4*)&zW[lane * 8];
  float4 w2 = *(const float4*)&zW[lane * 8 + 4];
  float4 w3 = *(const float4*)&zW[512 + lane * 8];
  float4 w4 = *(const float4*)&zW[512 + lane * 8 + 4];
  for (int r = wave; r < S_LEN * BATCH; r += 1024) {
    const float* hf  = hs + (size_t)r * HDIM;
    const float* hbk = hs + (size_t)(S_LEN * BATCH + r) * HDIM;
    float4 a1 = *(const float4*)&hf[lane * 8];
    float4 a2 = *(const float4*)&hf[lane * 8 + 4];
    float4 b1 = *(const float4*)&hbk[lane * 8];
    float4 b2 = *(const float4*)&hbk[lane * 8 + 4];
    float acc = a1.x * w1.x + a1.y * w1.y + a1.z * w1.z + a1.w * w1.w
              + a2.x * w2.x + a2.y * w2.y + a2.z * w2.z + a2.w * w2.w
              + b1.x * w3.x + b1.y * w3.y + b1.z * w3.z + b1.w * w3.w
              + b2.x * w4.x + b2.y * w4.y + b2.z * w4.z + b2.w * w4.w;
#pragma unroll
    for (int off = 32; off > 0; off >>= 1) acc += __shfl_down(acc, off, 64);
    if (lane == 0) {
      float p = 1.f / (1.f + expf(-(acc + zb)));
      out[r] = p;
      out[S_LEN * BATCH + r] = (noise[r] < p) ? 1.f : 0.f;
    }
  }
}

// ---------------- Phase D: per-column stable compaction ----------------
__global__ __launch_bounds__(256) void rat_kernel(
    const int* __restrict__ sent, float* __restrict__ out)
{
  const int b = blockIdx.x;
  const int s = threadIdx.x;
  __shared__ int ps[256];
  const int z = (out[S_LEN * BATCH + s * BATCH + b] > 0.5f) ? 1 : 0;
  ps[s] = z;
  __syncthreads();
#pragma unroll
  for (int off = 1; off < 256; off <<= 1) {
    int v = (s >= off) ? ps[s - off] : 0;
    __syncthreads();
    ps[s] += v;
    __syncthreads();
  }
  const int incl  = ps[s];
  const int total = ps[255];
  const int pos   = incl - z;
  if (z) out[2 * S_LEN * BATCH + pos * BATCH + b] = (float)sent[s * BATCH + b];
  if (s >= total) out[2 * S_LEN * BATCH + s * BATCH + b] = 0.f;
  if (s == 0) out[3 * S_LEN * BATCH + b] = (float)total;
}

extern "C" void kernel_launch(void* const* d_in, const int* in_sizes, int n_in,
                              void* d_out, int out_size, void* d_ws, size_t ws_size,
                              hipStream_t stream)
{
  const int*   sent  = (const int*)  d_in[0];
  const float* noise = (const float*)d_in[1];
  const float* emb   = (const float*)d_in[2];
  const float* Wih_f = (const float*)d_in[3];
  const float* Whh_f = (const float*)d_in[4];
  const float* bih_f = (const float*)d_in[5];
  const float* bhh_f = (const float*)d_in[6];
  const float* Wih_b = (const float*)d_in[7];
  const float* Whh_b = (const float*)d_in[8];
  const float* bih_b = (const float*)d_in[9];
  const float* bhh_b = (const float*)d_in[10];
  const float* zW    = (const float*)d_in[11];
  const float* zb    = (const float*)d_in[12];
  float* out = (float*)d_out;

  float* base = (float*)d_ws;
  unsigned* cnt = (unsigned*)base;                         // 1 KB
  float* hs = base + 256;                                  // 67.1 MB
  float* gi = hs + (size_t)2 * S_LEN * HDIM * BATCH;       // rest

  const size_t HS_BYTES = (size_t)2 * S_LEN * HDIM * BATCH * 4;
  const size_t GI_FULL  = (size_t)2 * S_LEN * 3 * HDIM * BATCH * 4;   // 201.3 MB
  const bool full = ws_size >= 1024 + HS_BYTES + GI_FULL;

  (void)hipMemsetAsync(cnt, 0, 1024, stream);
  if (full) {
    gi_gemm<<<dim3(128, 12, 2), 512, 0, stream>>>(
        sent, emb, Wih_f, bih_f, Wih_b, bih_b, gi, 0, S_LEN);
    scan_kernel<<<dim3(256), 256, 0, stream>>>(
        gi, hs, Whh_f, bhh_f, Whh_b, bhh_b, cnt, 0, S_LEN);
  } else {
    for (int c = 0; c < 4; ++c) {
      gi_gemm<<<dim3(32, 12, 2), 512, 0, stream>>>(
          sent, emb, Wih_f, bih_f, Wih_b, bih_b, gi, 64 * c, 64);
      scan_kernel<<<dim3(256), 256, 0, stream>>>(
          gi, hs, Whh_f, bhh_f, Whh_b, bhh_b, cnt, 64 * c, 64);
    }
  }
  pz_kernel<<<dim3(256), 256, 0, stream>>>(hs, zW, zb, noise, out);
  rat_kernel<<<dim3(BATCH), 256, 0, stream>>>(sent, out);
}